// Round 17
// baseline (558.506 us; speedup 1.0000x reference)
//
#include <hip/hip_runtime.h>
#include <hip/hip_bf16.h>
#include <math.h>

// Problem constants
constexpr int Bc = 4;
constexpr int Sc = 2048;
constexpr int Dc = 512;
constexpr int Hc = 8;
constexpr int DHc = 64;
constexpr int Lc = 4;
constexpr int DFFc = 2048;
constexpr int Tc = Bc * Sc;   // 8192 tokens
constexpr int QKVW = 3 * Dc;  // 1536

typedef __attribute__((ext_vector_type(8))) short short8;
typedef __attribute__((ext_vector_type(4))) float f32x4;
typedef __attribute__((ext_vector_type(4))) float float4v;
typedef __attribute__((ext_vector_type(4))) unsigned int uint4v;
typedef __attribute__((ext_vector_type(2))) unsigned int uint2v;

static __device__ __forceinline__ float u16tof(unsigned int u) {
  return __uint_as_float(u << 16);
}
static __device__ __forceinline__ unsigned short ftobf(float f) {
  __hip_bfloat16 h = __float2bfloat16(f);
  return *reinterpret_cast<unsigned short*>(&h);
}
static __device__ __forceinline__ void gload_lds16(const void* g, void* l) {
  __builtin_amdgcn_global_load_lds(
      (const __attribute__((address_space(1))) void*)g,
      (__attribute__((address_space(3))) void*)l, 16, 0, 0);
}

// LDS chunk-swizzle helpers for attention (16B-chunk XOR, conflict-free b128)
static __device__ __forceinline__ int swzK(int row, int col) {  // width 64
  return row * 64 + ((((col >> 3) ^ (row & 7)) << 3) | (col & 7));
}
static __device__ __forceinline__ int swzW(int row, int col) {  // width 192
  return row * 192 + ((((col >> 3) ^ (row & 7)) << 3) | (col & 7));
}
// GEMM-family granule permutation
static __device__ __forceinline__ int gperm(int row, int ch) {
  return (row >> 1) * 8 + (((((row & 1) << 2) | ch)) ^ ((row >> 1) & 7));
}

// ---------------------------------------------------------------------------
// Merged fp32 -> bf16 weight conversion (all 4 tensors, one launch, x4 vec)
// ---------------------------------------------------------------------------
__global__ __launch_bounds__(256) void k_f2bf4(const float* __restrict__ p0,
                                               const float* __restrict__ p1,
                                               const float* __restrict__ p2,
                                               const float* __restrict__ p3,
                                               unsigned short* __restrict__ o0,
                                               unsigned short* __restrict__ o1,
                                               unsigned short* __restrict__ o2,
                                               unsigned short* __restrict__ o3,
                                               int n0, int n01, int n012, int n0123) {
  int i4 = (blockIdx.x * 256 + threadIdx.x) * 4;
  if (i4 >= n0123) return;
  const float* src;
  unsigned short* dst;
  int off;
  if (i4 < n0) { src = p0; dst = o0; off = i4; }
  else if (i4 < n01) { src = p1; dst = o1; off = i4 - n0; }
  else if (i4 < n012) { src = p2; dst = o2; off = i4 - n01; }
  else { src = p3; dst = o3; off = i4 - n012; }
  float4v v = *(const float4v*)&src[off];
  uint2v pk = {ftobf(v[0]) | ((unsigned int)ftobf(v[1]) << 16),
               ftobf(v[2]) | ((unsigned int)ftobf(v[3]) << 16)};
  *(uint2v*)&dst[off] = pk;
}

// ---------------------------------------------------------------------------
// Embed (vectorized x4): h = x @ W_in^T + b_in + pos ; also bf16 copy
// ---------------------------------------------------------------------------
__global__ __launch_bounds__(256) void k_embed(const float* __restrict__ x,
                                               const float* __restrict__ W_in,
                                               const float* __restrict__ b_in,
                                               const float* __restrict__ pos,
                                               float* __restrict__ h,
                                               unsigned short* __restrict__ hb) {
  int i4 = (blockIdx.x * 256 + threadIdx.x) * 4;
  int t = i4 >> 9;
  int d = i4 & 511;
  int s = t & (Sc - 1);
  float x0 = x[t * 2 + 0], x1 = x[t * 2 + 1];
  float4v w01 = *(const float4v*)&W_in[d * 2];
  float4v w23 = *(const float4v*)&W_in[d * 2 + 4];
  float4v pz = *(const float4v*)&pos[(size_t)s * Dc + d];
  float4v b4 = *(const float4v*)&b_in[d];
  float4v v;
  v[0] = x0 * w01[0] + x1 * w01[1] + b4[0] + pz[0];
  v[1] = x0 * w01[2] + x1 * w01[3] + b4[1] + pz[1];
  v[2] = x0 * w23[0] + x1 * w23[1] + b4[2] + pz[2];
  v[3] = x0 * w23[2] + x1 * w23[3] + b4[3] + pz[3];
  *(float4v*)&h[i4] = v;
  uint2v pk = {ftobf(v[0]) | ((unsigned int)ftobf(v[1]) << 16),
               ftobf(v[2]) | ((unsigned int)ftobf(v[3]) << 16)};
  *(uint2v*)&hb[i4] = pk;
}

// ---------------------------------------------------------------------------
// k_mgemm2: 128x128, BK=32, double-buffer with per-step drain, 32 KB LDS,
// (256,4) -> 4 blocks/CU. For grids that fill 4 blocks/CU (FF1: 1024).
//   MODE 0: +bias ; MODE 2: +bias, exact GELU
//   OUTBF: 1 -> bf16 out, 0 -> fp32 out
// ---------------------------------------------------------------------------
template <int MODE, int OUTBF>
__global__ __launch_bounds__(256, 4) void k_mgemm2(const unsigned short* __restrict__ A,
                                                   const unsigned short* __restrict__ W,
                                                   const float* __restrict__ bias,
                                                   void* __restrict__ Cout,
                                                   int M, int N, int K) {
  __shared__ short SMEM[2][2][512 * 8];
  const int tid = threadIdx.x;
  const int lane = tid & 63;
  const int wid = tid >> 6;
  const int wm = wid >> 1;
  const int wn = wid & 1;

  const int nwg = gridDim.x * gridDim.y;
  const int bid = blockIdx.y * gridDim.x + blockIdx.x;
  const int swz = (bid & 7) * (nwg >> 3) + (bid >> 3);
  const int m0 = (swz / gridDim.x) * 128;
  const int n0 = (swz % gridDim.x) * 128;

  int r0S, c0S, r1S, c1S;
  {
    int p = tid;
    int rp = p >> 3, q = (p & 7) ^ (rp & 7);
    r0S = (rp << 1) | (q >> 2);
    c0S = q & 3;
    p = tid + 256;
    rp = p >> 3;
    q = (p & 7) ^ (rp & 7);
    r1S = (rp << 1) | (q >> 2);
    c1S = q & 3;
  }
  const unsigned short* a0p = A + (size_t)(m0 + r0S) * K + c0S * 8;
  const unsigned short* a1p = A + (size_t)(m0 + r1S) * K + c1S * 8;
  const unsigned short* b0p = W + (size_t)(n0 + r0S) * K + c0S * 8;
  const unsigned short* b1p = W + (size_t)(n0 + r1S) * K + c1S * 8;
  const int d0 = (tid & ~63) * 8;
  const int d1 = ((tid + 256) & ~63) * 8;

  f32x4 acc[4][4] = {};
  const int lr = lane & 15;
  const int chr = lane >> 4;

  gload_lds16(a0p, &SMEM[0][0][d0]);
  gload_lds16(a1p, &SMEM[0][0][d1]);
  gload_lds16(b0p, &SMEM[1][0][d0]);
  gload_lds16(b1p, &SMEM[1][0][d1]);
  __syncthreads();

  const int nsteps = K >> 5;
  int buf = 0;
  for (int s = 0; s < nsteps; ++s) {
    if (s + 1 < nsteps) {
      const int ko = (s + 1) << 5;
      gload_lds16(a0p + ko, &SMEM[0][buf ^ 1][d0]);
      gload_lds16(a1p + ko, &SMEM[0][buf ^ 1][d1]);
      gload_lds16(b0p + ko, &SMEM[1][buf ^ 1][d0]);
      gload_lds16(b1p + ko, &SMEM[1][buf ^ 1][d1]);
    }
    short8 af[4], bfr[4];
#pragma unroll
    for (int mi = 0; mi < 4; ++mi)
      af[mi] = *(const short8*)&SMEM[0][buf][gperm(wm * 64 + mi * 16 + lr, chr) * 8];
#pragma unroll
    for (int ni = 0; ni < 4; ++ni)
      bfr[ni] = *(const short8*)&SMEM[1][buf][gperm(wn * 64 + ni * 16 + lr, chr) * 8];
#pragma unroll
    for (int mi = 0; mi < 4; ++mi)
#pragma unroll
      for (int ni = 0; ni < 4; ++ni)
        acc[mi][ni] = __builtin_amdgcn_mfma_f32_16x16x32_bf16(
            af[mi], bfr[ni], acc[mi][ni], 0, 0, 0);
    __syncthreads();
    buf ^= 1;
  }

  // LDS-transpose epilogue
  float* cw = (float*)&SMEM[0][0][0] + wid * (16 * 68);
  const int cj = lane & 15;
  const int rj4 = (lane >> 4) * 4;
  const int rrd = lane >> 3;
  const int crd = (lane & 7) * 8;
#pragma unroll
  for (int mi = 0; mi < 4; ++mi) {
#pragma unroll
    for (int ni = 0; ni < 4; ++ni) {
      float bn = bias[n0 + wn * 64 + ni * 16 + cj];
#pragma unroll
      for (int j = 0; j < 4; ++j) {
        float v = acc[mi][ni][j] + bn;
        if (MODE == 2) v = 0.5f * v * (1.0f + erff(v * 0.70710678118654752f));
        cw[(rj4 + j) * 68 + ni * 16 + cj] = v;
      }
    }
    __builtin_amdgcn_sched_barrier(0);
#pragma unroll
    for (int t = 0; t < 2; ++t) {
      int rl = t * 8 + rrd;
      float4v v0 = *(const float4v*)&cw[rl * 68 + crd];
      float4v v1 = *(const float4v*)&cw[rl * 68 + crd + 4];
      size_t gbase = (size_t)(m0 + wm * 64 + mi * 16 + rl) * N +
                     (n0 + wn * 64 + crd);
      if (OUTBF) {
        unsigned int w0 = ftobf(v0[0]) | ((unsigned int)ftobf(v0[1]) << 16);
        unsigned int w1 = ftobf(v0[2]) | ((unsigned int)ftobf(v0[3]) << 16);
        unsigned int w2 = ftobf(v1[0]) | ((unsigned int)ftobf(v1[1]) << 16);
        unsigned int w3 = ftobf(v1[2]) | ((unsigned int)ftobf(v1[3]) << 16);
        uint4v pk = {w0, w1, w2, w3};
        *(uint4v*)&((unsigned short*)Cout)[gbase] = pk;
      } else {
        *(float4v*)&((float*)Cout)[gbase] = v0;
        *(float4v*)&((float*)Cout)[gbase + 4] = v1;
      }
    }
    __builtin_amdgcn_sched_barrier(0);
  }
}

// ---------------------------------------------------------------------------
// k_mgemm3: 128x128, BK=32, triple-buffer counted-vmcnt no-drain pipeline,
// 48 KB LDS, (256,3) -> 3 blocks/CU. For grids at <=3 blocks/CU (QKV: 768,
// Wo/W2: 256) where the no-drain pipeline wins and occupancy isn't sacrificed.
// ---------------------------------------------------------------------------
template <int MODE, int OUTBF>
__global__ __launch_bounds__(256, 3) void k_mgemm3(const unsigned short* __restrict__ A,
                                                   const unsigned short* __restrict__ W,
                                                   const float* __restrict__ bias,
                                                   void* __restrict__ Cout,
                                                   int M, int N, int K) {
  __shared__ short SMEM[3][2][512 * 8];  // 48 KB
  const int tid = threadIdx.x;
  const int lane = tid & 63;
  const int wid = tid >> 6;
  const int wm = wid >> 1;
  const int wn = wid & 1;

  const int nwg = gridDim.x * gridDim.y;
  const int bid = blockIdx.y * gridDim.x + blockIdx.x;
  const int swz = (bid & 7) * (nwg >> 3) + (bid >> 3);
  const int m0 = (swz / gridDim.x) * 128;
  const int n0 = (swz % gridDim.x) * 128;

  int r0S, c0S, r1S, c1S;
  {
    int p = tid;
    int rp = p >> 3, q = (p & 7) ^ (rp & 7);
    r0S = (rp << 1) | (q >> 2);
    c0S = q & 3;
    p = tid + 256;
    rp = p >> 3;
    q = (p & 7) ^ (rp & 7);
    r1S = (rp << 1) | (q >> 2);
    c1S = q & 3;
  }
  const unsigned short* a0p = A + (size_t)(m0 + r0S) * K + c0S * 8;
  const unsigned short* a1p = A + (size_t)(m0 + r1S) * K + c1S * 8;
  const unsigned short* b0p = W + (size_t)(n0 + r0S) * K + c0S * 8;
  const unsigned short* b1p = W + (size_t)(n0 + r1S) * K + c1S * 8;
  const int d0 = (tid & ~63) * 8;
  const int d1 = ((tid + 256) & ~63) * 8;

  f32x4 acc[4][4] = {};
  const int lr = lane & 15;
  const int chr = lane >> 4;

#pragma unroll
  for (int t = 0; t < 2; ++t) {
    const int ko = t << 5;
    gload_lds16(a0p + ko, &SMEM[t][0][d0]);
    gload_lds16(a1p + ko, &SMEM[t][0][d1]);
    gload_lds16(b0p + ko, &SMEM[t][1][d0]);
    gload_lds16(b1p + ko, &SMEM[t][1][d1]);
  }

  const int nsteps = K >> 5;
  for (int s = 0; s < nsteps; ++s) {
    if (s + 1 < nsteps)
      asm volatile("s_waitcnt vmcnt(4)" ::: "memory");
    else
      asm volatile("s_waitcnt vmcnt(0)" ::: "memory");
    __builtin_amdgcn_s_barrier();
    __builtin_amdgcn_sched_barrier(0);

    if (s + 2 < nsteps) {
      const int ko = (s + 2) << 5;
      const int nb = (s + 2) % 3;
      gload_lds16(a0p + ko, &SMEM[nb][0][d0]);
      gload_lds16(a1p + ko, &SMEM[nb][0][d1]);
      gload_lds16(b0p + ko, &SMEM[nb][1][d0]);
      gload_lds16(b1p + ko, &SMEM[nb][1][d1]);
    }

    const int buf = s % 3;
    short8 af[4], bfr[4];
#pragma unroll
    for (int mi = 0; mi < 4; ++mi)
      af[mi] = *(const short8*)&SMEM[buf][0][gperm(wm * 64 + mi * 16 + lr, chr) * 8];
#pragma unroll
    for (int ni = 0; ni < 4; ++ni)
      bfr[ni] = *(const short8*)&SMEM[buf][1][gperm(wn * 64 + ni * 16 + lr, chr) * 8];
    asm volatile("s_waitcnt lgkmcnt(0)" ::: "memory");
    __builtin_amdgcn_sched_barrier(0);
#pragma unroll
    for (int mi = 0; mi < 4; ++mi)
#pragma unroll
      for (int ni = 0; ni < 4; ++ni)
        acc[mi][ni] = __builtin_amdgcn_mfma_f32_16x16x32_bf16(
            af[mi], bfr[ni], acc[mi][ni], 0, 0, 0);
  }
  __syncthreads();

  // LDS-transpose epilogue
  float* cw = (float*)&SMEM[0][0][0] + wid * (16 * 68);
  const int cj = lane & 15;
  const int rj4 = (lane >> 4) * 4;
  const int rrd = lane >> 3;
  const int crd = (lane & 7) * 8;
#pragma unroll
  for (int mi = 0; mi < 4; ++mi) {
#pragma unroll
    for (int ni = 0; ni < 4; ++ni) {
      float bn = bias[n0 + wn * 64 + ni * 16 + cj];
#pragma unroll
      for (int j = 0; j < 4; ++j) {
        float v = acc[mi][ni][j] + bn;
        if (MODE == 2) v = 0.5f * v * (1.0f + erff(v * 0.70710678118654752f));
        cw[(rj4 + j) * 68 + ni * 16 + cj] = v;
      }
    }
    __builtin_amdgcn_sched_barrier(0);
#pragma unroll
    for (int t = 0; t < 2; ++t) {
      int rl = t * 8 + rrd;
      float4v v0 = *(const float4v*)&cw[rl * 68 + crd];
      float4v v1 = *(const float4v*)&cw[rl * 68 + crd + 4];
      size_t gbase = (size_t)(m0 + wm * 64 + mi * 16 + rl) * N +
                     (n0 + wn * 64 + crd);
      if (OUTBF) {
        unsigned int w0 = ftobf(v0[0]) | ((unsigned int)ftobf(v0[1]) << 16);
        unsigned int w1 = ftobf(v0[2]) | ((unsigned int)ftobf(v0[3]) << 16);
        unsigned int w2 = ftobf(v1[0]) | ((unsigned int)ftobf(v1[1]) << 16);
        unsigned int w3 = ftobf(v1[2]) | ((unsigned int)ftobf(v1[3]) << 16);
        uint4v pk = {w0, w1, w2, w3};
        *(uint4v*)&((unsigned short*)Cout)[gbase] = pk;
      } else {
        *(float4v*)&((float*)Cout)[gbase] = v0;
        *(float4v*)&((float*)Cout)[gbase + 4] = v1;
      }
    }
    __builtin_amdgcn_sched_barrier(0);
  }
}

// ---------------------------------------------------------------------------
// Windowed causal attention, MFMA. qkv bf16 [T][1536]. PV kb-range trimmed.
// LDS 48 KB (Ps aliases Ks), 3 blocks/CU. K staged via gload_lds
// (pre-swizzled source, linear dest; slot s of row r = source chunk s^(r&7)).
// ---------------------------------------------------------------------------
__global__ __launch_bounds__(256, 3) void k_attn(const unsigned short* __restrict__ qkv,
                                                 unsigned short* __restrict__ o) {
  __shared__ unsigned short KPs[192 * 64];  // K rows, then reused as P
  __shared__ unsigned short Vt[64 * 192];

  const int tid = threadIdx.x;
  const int lane = tid & 63;
  const int w = tid >> 6;
  const int idx = blockIdx.x;
  const int qb = idx & 31;
  const int hh = (idx >> 5) & 7;
  const int b = idx >> 8;
  const int q0 = qb * 64;
  const int kstart = max(0, q0 - 128);
  const int nk = q0 + 64 - kstart;  // 64 (qb==0) or 192

  {
    const unsigned short* kbase = qkv + (size_t)(b * Sc + kstart) * QKVW + Dc + hh * DHc;
    const int ng = nk * 8;
    for (int c = tid; c < ng; c += 256) {
      int row = c >> 3, slot = c & 7;
      int sch = slot ^ (row & 7);
      gload_lds16(kbase + (size_t)row * QKVW + sch * 8,
                  (char*)KPs + (c & ~63) * 16);
    }
  }
  for (int c = tid; c < (nk >> 1) * 8; c += 256) {
    int jp = c >> 3, ch = c & 7;
    int j = jp * 2;
    const unsigned short* base =
        &qkv[(size_t)(b * Sc + kstart + j) * QKVW + 2 * Dc + hh * DHc + ch * 8];
    short8 v0 = *(const short8*)base;
    short8 v1 = *(const short8*)(base + QKVW);
#pragma unroll
    for (int i = 0; i < 8; ++i) {
      unsigned int pk = (unsigned short)v0[i] | ((unsigned int)(unsigned short)v1[i] << 16);
      *(unsigned int*)&Vt[swzW(ch * 8 + i, j)] = pk;
    }
  }
  if (nk < 192) {  // qb==0: zero Vt cols [64,192) so P*garbage can't NaN
    for (int c = tid; c < 64 * 64; c += 256) {
      int d = c >> 6, jo = c & 63;
      *(unsigned int*)&Vt[swzW(d, 64 + jo * 2)] = 0;
    }
  }

  const int qg = q0 + w * 16 + (lane & 15);
  const int kg8 = (lane >> 4) * 8;
  const unsigned short* qp = &qkv[(size_t)(b * Sc + qg) * QKVW + hh * DHc + kg8];
  short8 bq0 = *(const short8*)qp;
  short8 bq1 = *(const short8*)(qp + 32);
  __syncthreads();  // drains vmcnt (gload_lds) + lgkm (ds_writes)

  const int jb = max(0, q0 + w * 16 - 128) - kstart;

  f32x4 sacc[9];
#pragma unroll
  for (int t = 0; t < 9; ++t) {
    int key = jb + t * 16 + (lane & 15);
    short8 a0 = *(const short8*)&KPs[swzK(key, kg8)];
    short8 a1 = *(const short8*)&KPs[swzK(key, 32 + kg8)];
    f32x4 z = {0.f, 0.f, 0.f, 0.f};
    z = __builtin_amdgcn_mfma_f32_16x16x32_bf16(a0, bq0, z, 0, 0, 0);
    sacc[t] = __builtin_amdgcn_mfma_f32_16x16x32_bf16(a1, bq1, z, 0, 0, 0);
  }

  const int rj = (lane >> 4) * 4;
  float mx = -1e30f;
#pragma unroll
  for (int t = 0; t < 9; ++t) {
#pragma unroll
    for (int j = 0; j < 4; ++j) {
      int kglob = kstart + jb + t * 16 + rj + j;
      bool valid = (kglob <= qg) && (kglob + 128 >= qg);
      float s = valid ? sacc[t][j] * 0.125f : -1e30f;
      sacc[t][j] = s;
      mx = fmaxf(mx, s);
    }
  }
  mx = fmaxf(mx, __shfl_xor(mx, 16));
  mx = fmaxf(mx, __shfl_xor(mx, 32));
  float sum = 0.f;
#pragma unroll
  for (int t = 0; t < 9; ++t)
#pragma unroll
    for (int j = 0; j < 4; ++j) {
      float e = __expf(sacc[t][j] - mx);
      sacc[t][j] = e;
      sum += e;
    }
  sum += __shfl_xor(sum, 16);
  sum += __shfl_xor(sum, 32);
  const float inv = 1.0f / sum;

  __syncthreads();  // all K reads complete; hand KPs over to P storage

  const int prow = w * 16 + (lane & 15);
#pragma unroll
  for (int t = 0; t < 9; ++t) {
    int c0 = jb + t * 16 + rj;
    unsigned int p0 = ftobf(sacc[t][0] * inv) |
                      ((unsigned int)ftobf(sacc[t][1] * inv) << 16);
    unsigned int p1 = ftobf(sacc[t][2] * inv) |
                      ((unsigned int)ftobf(sacc[t][3] * inv) << 16);
    *(unsigned int*)&KPs[swzW(prow, c0)] = p0;
    *(unsigned int*)&KPs[swzW(prow, c0 + 2)] = p1;
  }
  {
    int g2 = (lane >> 4) * 2;
    for (int col = g2; col < jb; col += 8)
      *(unsigned int*)&KPs[swzW(prow, col)] = 0;
    for (int col = jb + 144 + g2; col < 192; col += 8)
      *(unsigned int*)&KPs[swzW(prow, col)] = 0;
  }
  const int kb0 = jb >> 5;
  const int kbend = min(6, (jb + 144 + 31) >> 5);
  f32x4 oacc[4] = {};
  for (int kb = kb0; kb < kbend; ++kb) {
    short8 pa = *(const short8*)&KPs[swzW(prow, kb * 32 + kg8)];
#pragma unroll
    for (int dt = 0; dt < 4; ++dt) {
      short8 vb = *(const short8*)&Vt[swzW(dt * 16 + (lane & 15), kb * 32 + kg8)];
      oacc[dt] = __builtin_amdgcn_mfma_f32_16x16x32_bf16(pa, vb, oacc[dt], 0, 0, 0);
    }
  }
  const int cj = lane & 15;
#pragma unroll
  for (int j = 0; j < 4; ++j)
#pragma unroll
    for (int dt = 0; dt < 4; ++dt)
      o[(size_t)(b * Sc + q0 + w * 16 + rj + j) * Dc + hh * DHc + dt * 16 + cj] =
          ftobf(oacc[dt][j]);
}

// ---------------------------------------------------------------------------
// Residual + LayerNorm: h = LN(h + raw) over D=512; writes h fp32 + hb bf16.
// ---------------------------------------------------------------------------
__global__ __launch_bounds__(256) void k_lnr(float* __restrict__ h,
                                             const float* __restrict__ raw,
                                             const float* __restrict__ g,
                                             const float* __restrict__ bta,
                                             unsigned short* __restrict__ outb) {
  const int wid = threadIdx.x >> 6;
  const int lane = threadIdx.x & 63;
  const int t = blockIdx.x * 4 + wid;
  const float4v* hrow = (const float4v*)(h + (size_t)t * Dc);
  const float4v* rrow = (const float4v*)(raw + (size_t)t * Dc);
  float4v v[2];
  float sum = 0.0f, sq = 0.0f;
#pragma unroll
  for (int i = 0; i < 2; ++i) {
    float4v hv = hrow[lane + i * 64];
    float4v rv = rrow[lane + i * 64];
#pragma unroll
    for (int c = 0; c < 4; ++c) {
      float xv = rv[c] + hv[c];
      v[i][c] = xv;
      sum += xv;
      sq += xv * xv;
    }
  }
#pragma unroll
  for (int off = 32; off; off >>= 1) {
    sum += __shfl_xor(sum, off);
    sq += __shfl_xor(sq, off);
  }
  float m = sum * (1.0f / 512.0f);
  float var = sq * (1.0f / 512.0f) - m * m;
  float rstd = rsqrtf(var + 1e-5f);
  float4v* orow = (float4v*)(h + (size_t)t * Dc);
  unsigned int* brow = (unsigned int*)(outb + (size_t)t * Dc);
#pragma unroll
  for (int i = 0; i < 2; ++i) {
    int d4 = (lane + i * 64) * 4;
    float4v ov;
#pragma unroll
    for (int c = 0; c < 4; ++c)
      ov[c] = (v[i][c] - m) * rstd * g[d4 + c] + bta[d4 + c];
    orow[lane + i * 64] = ov;
    unsigned int p0 = ftobf(ov[0]) | ((unsigned int)ftobf(ov[1]) << 16);
    unsigned int p1 = ftobf(ov[2]) | ((unsigned int)ftobf(ov[3]) << 16);
    brow[(lane + i * 64) * 2] = p0;
    brow[(lane + i * 64) * 2 + 1] = p1;
  }
}

// ---------------------------------------------------------------------------
// Head (fp32, float4-vectorized): mu | clipped log_sigma
// ---------------------------------------------------------------------------
__global__ __launch_bounds__(256) void k_head(const float* __restrict__ h,
                                              const float* __restrict__ Wh,
                                              const float* __restrict__ bh,
                                              float* __restrict__ outp) {
  const int wid = threadIdx.x >> 6;
  const int lane = threadIdx.x & 63;
  const int t = blockIdx.x * 4 + wid;
  const float4v* row4 = (const float4v*)(h + (size_t)t * Dc);
  const float4v* w0r = (const float4v*)(Wh + 0 * Dc);
  const float4v* w1r = (const float4v*)(Wh + 1 * Dc);
  const float4v* w2r = (const float4v*)(Wh + 2 * Dc);
  const float4v* w3r = (const float4v*)(Wh + 3 * Dc);
  float a0 = 0, a1 = 0, a2 = 0, a3 = 0;
#pragma unroll
  for (int i = 0; i < 2; ++i) {
    int d4 = lane + i * 64;
    float4v xv = row4[d4];
    float4v v0 = w0r[d4];
    float4v v1 = w1r[d4];
    float4v v2 = w2r[d4];
    float4v v3 = w3r[d4];
#pragma unroll
    for (int c = 0; c < 4; ++c) {
      a0 += xv[c] * v0[c];
      a1 += xv[c] * v1[c];
      a2 += xv[c] * v2[c];
      a3 += xv[c] * v3[c];
    }
  }
#pragma unroll
  for (int off = 32; off; off >>= 1) {
    a0 += __shfl_xor(a0, off);
    a1 += __shfl_xor(a1, off);
    a2 += __shfl_xor(a2, off);
    a3 += __shfl_xor(a3, off);
  }
  if (lane == 0) {
    outp[(size_t)t * 2 + 0] = a0 + bh[0];
    outp[(size_t)t * 2 + 1] = a1 + bh[1];
    outp[(size_t)Tc * 2 + (size_t)t * 2 + 0] = fminf(fmaxf(a2 + bh[2], -6.0f), 1.5f);
    outp[(size_t)Tc * 2 + (size_t)t * 2 + 1] = fminf(fmaxf(a3 + bh[3], -6.0f), 1.5f);
  }
}

// ---------------------------------------------------------------------------
extern "C" void kernel_launch(void* const* d_in, const int* in_sizes, int n_in,
                              void* d_out, int out_size, void* d_ws, size_t ws_size,
                              hipStream_t stream) {
  const float* x    = (const float*)d_in[0];
  const float* W_in = (const float*)d_in[1];
  const float* b_in = (const float*)d_in[2];
  const float* pos  = (const float*)d_in[3];
  const float* Wqkv = (const float*)d_in[4];
  const float* bqkv = (const float*)d_in[5];
  const float* Wo   = (const float*)d_in[6];
  const float* bo   = (const float*)d_in[7];
  const float* W1   = (const float*)d_in[8];
  const float* b1   = (const float*)d_in[9];
  const float* W2   = (const float*)d_in[10];
  const float* b2   = (const float*)d_in[11];
  const float* ln1g = (const float*)d_in[12];
  const float* ln1b = (const float*)d_in[13];
  const float* ln2g = (const float*)d_in[14];
  const float* ln2b = (const float*)d_in[15];
  const float* Wh   = (const float*)d_in[16];
  const float* bh   = (const float*)d_in[17];
  float* out = (float*)d_out;

  char* p = (char*)d_ws;
  float* h   = (float*)p;          p += (size_t)Tc * Dc * 4;   // residual stream fp32
  float* t2  = (float*)p;          p += (size_t)Tc * Dc * 4;   // raw GEMM out fp32
  unsigned short* hb  = (unsigned short*)p; p += (size_t)Tc * Dc * 2;
  unsigned short* ob  = (unsigned short*)p; p += (size_t)Tc * Dc * 2;
  unsigned short* big = (unsigned short*)p; p += (size_t)Tc * DFFc * 2;
  unsigned short* wqb = (unsigned short*)p; p += (size_t)Lc * QKVW * Dc * 2;
  unsigned short* wob = (unsigned short*)p; p += (size_t)Lc * Dc * Dc * 2;
  unsigned short* w1b = (unsigned short*)p; p += (size_t)Lc * DFFc * Dc * 2;
  unsigned short* w2b = (unsigned short*)p; p += (size_t)Lc * Dc * DFFc * 2;

  const int nq = Lc * QKVW * Dc;
  const int no = Lc * Dc * Dc;
  const int n1 = Lc * DFFc * Dc;
  const int n2 = Lc * Dc * DFFc;
  const int ntot = nq + no + n1 + n2;
  k_f2bf4<<<ntot / 1024, 256, 0, stream>>>(Wqkv, Wo, W1, W2, wqb, wob, w1b, w2b,
                                           nq, nq + no, nq + no + n1, ntot);

  k_embed<<<(Tc * Dc) / 1024, 256, 0, stream>>>(x, W_in, b_in, pos, h, hb);

  for (int l = 0; l < Lc; ++l) {
    const unsigned short* wq_l = wqb + (size_t)l * QKVW * Dc;
    const unsigned short* wo_l = wob + (size_t)l * Dc * Dc;
    const unsigned short* w1_l = w1b + (size_t)l * DFFc * Dc;
    const unsigned short* w2_l = w2b + (size_t)l * Dc * DFFc;

    // qkv = hb @ Wqkv^T + bqkv  (bf16 out) -- grid 768 = 3 blocks/CU:
    // k_mgemm3's co-residency point; no-drain pipeline wins here (r14 vs r15)
    k_mgemm3<0, 1><<<dim3(QKVW / 128, Tc / 128), 256, 0, stream>>>(
        hb, wq_l, bqkv + (size_t)l * QKVW, big, Tc, QKVW, Dc);

    k_attn<<<Bc * Hc * (Sc / 64), 256, 0, stream>>>(big, ob);

    // t2 = ob @ Wo^T + bo  (fp32 raw) -- small grid: 3-buf no-drain
    k_mgemm3<0, 0><<<dim3(Dc / 128, Tc / 128), 256, 0, stream>>>(
        ob, wo_l, bo + (size_t)l * Dc, t2, Tc, Dc, Dc);

    // h = LN1(h + t2); hb = bf16(h)
    k_lnr<<<Tc / 4, 256, 0, stream>>>(h, t2, ln1g + (size_t)l * Dc,
                                      ln1b + (size_t)l * Dc, hb);

    // big = gelu(hb @ W1^T + b1)  (bf16 out) -- grid 1024 = 4 blocks/CU:
    // k_mgemm2's co-residency point (occupancy wins, r15)
    k_mgemm2<2, 1><<<dim3(DFFc / 128, Tc / 128), 256, 0, stream>>>(
        hb, w1_l, b1 + (size_t)l * DFFc, big, Tc, DFFc, Dc);

    // t2 = big @ W2^T + b2  (fp32 raw) -- small grid, K=2048: 3-buf no-drain
    k_mgemm3<0, 0><<<dim3(Dc / 128, Tc / 128), 256, 0, stream>>>(
        big, w2_l, b2 + (size_t)l * Dc, t2, Tc, Dc, DFFc);

    // h = LN2(h + t2); hb = bf16(h)
    k_lnr<<<Tc / 4, 256, 0, stream>>>(h, t2, ln2g + (size_t)l * Dc,
                                      ln2b + (size_t)l * Dc, hb);
  }

  k_head<<<Tc / 4, 256, 0, stream>>>(h, Wh, bh, out);
}